// Round 4
// baseline (364.813 us; speedup 1.0000x reference)
//
#include <hip/hip_runtime.h>
#include <math.h>

#define Hh 80
#define Ww 80
#define HW 6400
#define NB 4

typedef _Float16 half8 __attribute__((ext_vector_type(8)));
typedef _Float16 half4v __attribute__((ext_vector_type(4)));
typedef float f32x16 __attribute__((ext_vector_type(16)));

// ---------------------------------------------------------------------------
// Weight transpose for 1x1 convs: OIHW -> [ci][co]
// ---------------------------------------------------------------------------
__global__ void wt_kernel(const float* __restrict__ src, float* __restrict__ dst,
                          int CO, int CI, int taps) {
    int idx = blockIdx.x * 256 + threadIdx.x;
    int total = CO * CI * taps;
    if (idx >= total) return;
    int co = idx % CO;
    int kt = idx / CO;
    int t  = kt % taps;
    int ci = kt / taps;
    dst[idx] = src[(co * CI + ci) * taps + t];
}

// ---------------------------------------------------------------------------
// Pack conv weights OIHW fp32 -> fp16 MFMA A-fragment blob:
// flat = ((((CT*NC + c)*9 + tap)*2 + h)*64 + lane)*8 + j
//   co = CT*32 + (lane&31);  ci = c*32 + h*16 + (lane>>5)*8 + j
// ---------------------------------------------------------------------------
__global__ void wblob_kernel(const float* __restrict__ src, _Float16* __restrict__ dst,
                             int CI, int taps) {
    int d = blockIdx.x * 256 + threadIdx.x;
    int NC = CI / 32;
    int total = 128 * CI * taps;
    if (d >= total) return;
    int j = d & 7;
    int l = (d >> 3) & 63;
    int h = (d >> 9) & 1;
    int rest = d >> 10;
    int tap = rest % taps;
    rest /= taps;
    int c = rest % NC;
    int CT = rest / NC;
    int co = CT * 32 + (l & 31);
    int ci = c * 32 + h * 16 + (l >> 5) * 8 + j;
    dst[d] = (_Float16)src[((size_t)co * CI + ci) * taps + tap];
}

// ---------------------------------------------------------------------------
// fp32 NCHW -> fp16 NHWC transpose. grid (100, N), block 256, 64-site tiles.
// ---------------------------------------------------------------------------
template <int CI>
__global__ __launch_bounds__(256) void nchw_to_nhwc_h(
    const float* __restrict__ in, _Float16* __restrict__ out) {
    const int n = blockIdx.y, s0 = blockIdx.x * 64;
    const int t = threadIdx.x;
    constexpr int ST = CI + 8;
    __shared__ _Float16 T[64 * ST];
    for (int idx = t; idx < 64 * CI; idx += 256) {
        int ci = idx >> 6, sl = idx & 63;
        T[sl * ST + ci] = (_Float16)in[((size_t)n * CI + ci) * HW + s0 + sl];
    }
    __syncthreads();
    constexpr int NQ = CI / 8;
    for (int idx = t; idx < 64 * NQ; idx += 256) {
        int q = idx % NQ, sl = idx / NQ;
        *(int4*)(out + ((size_t)n * HW + s0 + sl) * CI + q * 8) =
            *(const int4*)(&T[sl * ST + q * 8]);
    }
}

// ---------------------------------------------------------------------------
// MFMA implicit-GEMM 3x3 conv, pad=1, fp16 NHWC in.
// Single-wave blocks (64 thr). Wave tile = 64co (2 co-tiles, B-frag reuse x2)
// x 32sp (8x4 2D region, 10x6 halo). Double-buffered LDS staging (32 ci/chunk).
// grid: (200 sp-tiles, 2 co-halves, N).
// ACT 1: leaky -> fp16 NHWC.  ACT 2: 10*tanh -> fp32 NHWC.
// ---------------------------------------------------------------------------
template <int CI, int ACT>
__global__ __launch_bounds__(64) void conv3x3_mfma(
    const _Float16* __restrict__ in, const _Float16* __restrict__ wblob,
    const float* __restrict__ bias, void* __restrict__ outp) {
    const int bx = blockIdx.x, ch = blockIdx.y, n = blockIdx.z;
    const int x0 = (bx % 10) * 8, y0 = (bx / 10) * 4;
    const int l = threadIdx.x;
    const int lane31 = l & 31, lhalf = l >> 5;
    const int lx = lane31 & 7, ly = lane31 >> 3;

    constexpr int NC = CI / 32;
    __shared__ _Float16 Bs[2][60 * 40];

    const int gy = y0 + ly, gx = x0 + lx;
    const int s = gy * 80 + gx;

    f32x16 acc0 = {}, acc1 = {};
    const int CT0 = ch * 2, CT1 = ch * 2 + 1;

    auto load_chunk = [&](int c, int4* r) {
#pragma unroll
        for (int k = 0; k < 4; ++k) {
            int idx = l + k * 64;
            int4 v = {0, 0, 0, 0};
            if (idx < 240) {
                int site = idx >> 2, q = idx & 3;
                int hy = site / 10, hx = site - hy * 10;
                int yy = y0 - 1 + hy, xx = x0 - 1 + hx;
                if (yy >= 0 && yy < Hh && xx >= 0 && xx < Ww)
                    v = *(const int4*)(in + (((size_t)n * HW + yy * 80 + xx) * CI + c * 32 + q * 8));
            }
            r[k] = v;
        }
    };
    auto write_chunk = [&](int buf, const int4* r) {
#pragma unroll
        for (int k = 0; k < 4; ++k) {
            int idx = l + k * 64;
            if (idx < 240) {
                int site = idx >> 2, q = idx & 3;
                *(int4*)&Bs[buf][site * 40 + q * 8] = r[k];
            }
        }
    };

    int4 r[4];
    load_chunk(0, r);
    write_chunk(0, r);
    __syncthreads();

    for (int c = 0; c < NC; ++c) {
        if (c + 1 < NC) load_chunk(c + 1, r);
        const _Float16* w0 = wblob + ((size_t)(CT0 * NC + c) * 18) * 512 + l * 8;
        const _Float16* w1 = wblob + ((size_t)(CT1 * NC + c) * 18) * 512 + l * 8;
        const _Float16* bp = &Bs[c & 1][0];
#pragma unroll
        for (int tap = 0; tap < 9; ++tap) {
            const int dy = tap / 3, dx = tap % 3;
            const _Float16* brow = bp + ((ly + dy) * 10 + (lx + dx)) * 40;
#pragma unroll
            for (int h = 0; h < 2; ++h) {
                half8 a0 = *(const half8*)(w0 + (tap * 2 + h) * 512);
                half8 a1 = *(const half8*)(w1 + (tap * 2 + h) * 512);
                half8 b = *(const half8*)(brow + h * 16 + lhalf * 8);
                acc0 = __builtin_amdgcn_mfma_f32_32x32x16_f16(a0, b, acc0, 0, 0, 0);
                acc1 = __builtin_amdgcn_mfma_f32_32x32x16_f16(a1, b, acc1, 0, 0, 0);
            }
        }
        if (c + 1 < NC) write_chunk((c + 1) & 1, r);
        __syncthreads();
    }

    // epilogue: D col(sp)=lane&31, row(co)=(reg&3)+8*(reg>>2)+4*(lane>>5)
    const size_t rowbase = ((size_t)n * HW + s) * 128;
#pragma unroll
    for (int ct = 0; ct < 2; ++ct) {
        const f32x16& acc = ct ? acc1 : acc0;
        const int co_base = (ch * 2 + ct) * 32;
#pragma unroll
        for (int q = 0; q < 4; ++q) {
            const int co0 = co_base + 8 * q + 4 * lhalf;
            float v[4];
#pragma unroll
            for (int i = 0; i < 4; ++i) {
                float vv = acc[q * 4 + i] + bias[co0 + i];
                if (ACT == 1) vv = (vv >= 0.f) ? vv : 0.1f * vv;
                else vv = 10.f * tanhf(vv);
                v[i] = vv;
            }
            if (ACT == 1) {
                half4v hv = {(_Float16)v[0], (_Float16)v[1], (_Float16)v[2], (_Float16)v[3]};
                *(half4v*)((_Float16*)outp + rowbase + co0) = hv;
            } else {
                float4 fv = {v[0], v[1], v[2], v[3]};
                *(float4*)((float*)outp + rowbase + co0) = fv;
            }
        }
    }
}

// ---------------------------------------------------------------------------
// 1x1 conv (fp32 GEMM 128x128 over spatial). grid: (100, N), block 256.
// wt layout: [ci][128co]. MODE 0: write v_s NHWC-16; MODE 1: write NCHW.
// ---------------------------------------------------------------------------
template <int MODE>
__global__ __launch_bounds__(256) void conv1x1_kernel(
    const float* __restrict__ in, const float* __restrict__ wt,
    const float* __restrict__ bias, float* __restrict__ out) {
    const int n = blockIdx.y;
    const int s0 = blockIdx.x * 64;
    const int t = threadIdx.x;
    const int sp_grp = t & 15;
    const int co_grp = t >> 4;

    __shared__ float Wl[16 * 128];
    __shared__ float Il[16 * 64];

    float acc[8][4];
#pragma unroll
    for (int i = 0; i < 8; ++i)
#pragma unroll
        for (int j = 0; j < 4; ++j) acc[i][j] = 0.f;

    for (int ch = 0; ch < 8; ++ch) {
        const int ci0 = ch * 16;
        __syncthreads();
        for (int i = t; i < 16 * 128; i += 256) Wl[i] = wt[ci0 * 128 + i];
        for (int i = t; i < 16 * 64; i += 256) {
            int ci = i >> 6, sp = i & 63;
            Il[i] = in[(size_t)(n * 128 + ci0 + ci) * HW + s0 + sp];
        }
        __syncthreads();
#pragma unroll
        for (int ci = 0; ci < 16; ++ci) {
            float4 a0 = *(const float4*)&Wl[ci * 128 + co_grp * 8];
            float4 a1 = *(const float4*)&Wl[ci * 128 + co_grp * 8 + 4];
            float4 b  = *(const float4*)&Il[ci * 64 + sp_grp * 4];
            float av[8] = {a0.x, a0.y, a0.z, a0.w, a1.x, a1.y, a1.z, a1.w};
            float bv[4] = {b.x, b.y, b.z, b.w};
#pragma unroll
            for (int i = 0; i < 8; ++i)
#pragma unroll
                for (int j = 0; j < 4; ++j)
                    acc[i][j] = fmaf(av[i], bv[j], acc[i][j]);
        }
    }

#pragma unroll
    for (int i = 0; i < 8; ++i) {
        const int co = co_grp * 8 + i;
        const float bv = bias[co];
        if (MODE == 0) {
            const int hd = co >> 4, dd = co & 15;
#pragma unroll
            for (int j = 0; j < 4; ++j) {
                int s = s0 + sp_grp * 4 + j;
                out[((size_t)(n * 8 + hd) * HW + s) * 16 + dd] = acc[i][j] + bv;
            }
        } else {
#pragma unroll
            for (int j = 0; j < 4; ++j)
                out[(size_t)(n * 128 + co) * HW + s0 + sp_grp * 4 + j] = acc[i][j] + bv;
        }
    }
}

// ---------------------------------------------------------------------------
// Deformable attention, channel-vectorized: thread = (site, 4-ch group).
// grid: (100, 8, 4), block 256 = 64 sites x 4 chgrp.
// v_s [nb][s][16] fp32; offs NHWC fp32 [n][s'][128]; att NCHW fp32.
// ---------------------------------------------------------------------------
__global__ __launch_bounds__(256) void deform_attn_kernel(
    const float* __restrict__ v_s, const float* __restrict__ offs,
    const float* __restrict__ ref, float* __restrict__ att) {
    const int n = blockIdx.z, hd = blockIdx.y;
    const int t = threadIdx.x;
    const int s = blockIdx.x * 64 + (t >> 2);
    const int d0 = (t & 3) * 4;
    const int nb = n * 8 + hd;

    const float4 cv = *(const float4*)&v_s[((size_t)nb * HW + s) * 16 + d0];
    const float rx = ref[(size_t)(n * HW + s) * 2 + 0] * 80.f - 0.5f;
    const float ry = ref[(size_t)(n * HW + s) * 2 + 1] * 80.f - 0.5f;

    const int e = (s >= 3200) ? 1 : 0;
    const float* ob0 = offs + ((size_t)n * HW + (2 * s - e * HW)) * 128 + hd * 16 + e;

    float4 sampled[8];
    float score[8];
#pragma unroll
    for (int p = 0; p < 8; ++p) {
        const float ox = ob0[2 * p];
        const float oy = ob0[128 + 2 * p];
        const float px = rx + ox;
        const float py = ry + oy;
        const float fx = floorf(px), fy = floorf(py);
        const int ix = (int)fx, iy = (int)fy;
        const float wx1 = px - fx, wy1 = py - fy;
        const float wx0 = 1.f - wx1, wy0 = 1.f - wy1;

        auto samp = [&](int xx, int yy) -> float4 {
            if (xx < 0 || xx >= Ww || yy < 0 || yy >= Hh) {
                float4 z = {0.f, 0.f, 0.f, 0.f};
                return z;
            }
            return *(const float4*)&v_s[((size_t)nb * HW + yy * Ww + xx) * 16 + d0];
        };
        const float4 v00 = samp(ix, iy);
        const float4 v01 = samp(ix + 1, iy);
        const float4 v10 = samp(ix, iy + 1);
        const float4 v11 = samp(ix + 1, iy + 1);
        const float w00 = wx0 * wy0, w01 = wx1 * wy0, w10 = wx0 * wy1, w11 = wx1 * wy1;
        float4 sv;
        sv.x = v00.x * w00 + v01.x * w01 + v10.x * w10 + v11.x * w11;
        sv.y = v00.y * w00 + v01.y * w01 + v10.y * w10 + v11.y * w11;
        sv.z = v00.z * w00 + v01.z * w01 + v10.z * w10 + v11.z * w11;
        sv.w = v00.w * w00 + v01.w * w01 + v10.w * w10 + v11.w * w11;
        sampled[p] = sv;
        float sc = sv.x * cv.x + sv.y * cv.y + sv.z * cv.z + sv.w * cv.w;
        sc += __shfl_xor(sc, 1);
        sc += __shfl_xor(sc, 2);
        score[p] = sc;
    }

    float m = score[0];
#pragma unroll
    for (int p = 1; p < 8; ++p) m = fmaxf(m, score[p]);
    float sum = 0.f, aw[8];
#pragma unroll
    for (int p = 0; p < 8; ++p) {
        aw[p] = __expf(score[p] - m);
        sum += aw[p];
    }
    const float inv = 1.f / sum;
    float4 o = {0.f, 0.f, 0.f, 0.f};
#pragma unroll
    for (int p = 0; p < 8; ++p) {
        o.x += aw[p] * sampled[p].x;
        o.y += aw[p] * sampled[p].y;
        o.z += aw[p] * sampled[p].z;
        o.w += aw[p] * sampled[p].w;
    }
    o.x *= inv; o.y *= inv; o.z *= inv; o.w *= inv;

    const size_t ob = ((size_t)n * 128 + hd * 16 + d0) * HW + s;
    att[ob] = o.x;
    att[ob + HW] = o.y;
    att[ob + 2 * HW] = o.z;
    att[ob + 3 * HW] = o.w;
}

// ---------------------------------------------------------------------------
extern "C" void kernel_launch(void* const* d_in, const int* in_sizes, int n_in,
                              void* d_out, int out_size, void* d_ws, size_t ws_size,
                              hipStream_t stream) {
    const float* query = (const float*)d_in[0];
    const float* value = (const float*)d_in[1];
    const float* ref   = (const float*)d_in[2];
    const float* co_w1 = (const float*)d_in[3];
    const float* co_b1 = (const float*)d_in[4];
    const float* co_w2 = (const float*)d_in[5];
    const float* co_b2 = (const float*)d_in[6];
    const float* co_w3 = (const float*)d_in[7];
    const float* co_b3 = (const float*)d_in[8];
    const float* co_w4 = (const float*)d_in[9];
    const float* co_b4 = (const float*)d_in[10];
    const float* val_w = (const float*)d_in[11];
    const float* val_b = (const float*)d_in[12];
    const float* out_w = (const float*)d_in[13];
    const float* out_b = (const float*)d_in[14];

    char* ws = (char*)d_ws;
    size_t o = 0;
    auto alloc = [&](size_t bytes) { char* p = ws + o; o += (bytes + 255) & ~(size_t)255; return p; };

    _Float16* wb2 = (_Float16*)alloc(147456 * 2);
    _Float16* wb3 = (_Float16*)alloc(147456 * 2);
    _Float16* wb4 = (_Float16*)alloc(147456 * 2);
    float* wtv = (float*)alloc(16384 * 4);
    float* wto = (float*)alloc(16384 * 4);
    char* vsR = alloc(3276800 * 4);            // v_s fp32 [32][6400][16]
    float* v_s = (float*)vsR;
    _Float16* wb1 = (_Float16*)vsR;            // alias: wb1 dead before v_s written
    char* R1 = alloc(3276800 * 4);
    _Float16* q_h = (_Float16*)R1;             // fp16 NHWC [4][6400][256] (13.1 MB)
    float* o4 = (float*)R1;                    // fp32 NHWC [4][6400][128]; q_h dead
    char* R2 = alloc(3276800 * 4);
    _Float16* hA = (_Float16*)R2;              // fp16 NHWC [4][6400][128]
    _Float16* hB = (_Float16*)(R2 + 3276800 * 2);
    float* att = (float*)R2;                   // alias: used after hA/hB dead

    // prep: transpose query, pack weights
    nchw_to_nhwc_h<256><<<dim3(100, NB), 256, 0, stream>>>(query, q_h);
    wblob_kernel<<<(294912 + 255) / 256, 256, 0, stream>>>(co_w1, wb1, 256, 9);
    wblob_kernel<<<(147456 + 255) / 256, 256, 0, stream>>>(co_w2, wb2, 128, 9);
    wblob_kernel<<<(147456 + 255) / 256, 256, 0, stream>>>(co_w3, wb3, 128, 9);
    wblob_kernel<<<(147456 + 255) / 256, 256, 0, stream>>>(co_w4, wb4, 128, 9);
    wt_kernel<<<(16384 + 255) / 256, 256, 0, stream>>>(val_w, wtv, 128, 128, 1);
    wt_kernel<<<(16384 + 255) / 256, 256, 0, stream>>>(out_w, wto, 128, 128, 1);

    // conv1 (must precede val-conv: wb1 aliases v_s region)
    conv3x3_mfma<256, 1><<<dim3(200, 2, NB), 64, 0, stream>>>(q_h, wb1, co_b1, hA);

    // v = 1x1 conv(value) -> v_s (NHWC-16 fp32)
    conv1x1_kernel<0><<<dim3(100, NB), 256, 0, stream>>>(value, wtv, val_b, v_s);

    // rest of offset conv stack
    conv3x3_mfma<128, 1><<<dim3(200, 2, NB), 64, 0, stream>>>(hA, wb2, co_b2, hB);
    conv3x3_mfma<128, 1><<<dim3(200, 2, NB), 64, 0, stream>>>(hB, wb3, co_b3, hA);
    conv3x3_mfma<128, 2><<<dim3(200, 2, NB), 64, 0, stream>>>(hA, wb4, co_b4, o4);

    // deformable attention -> att (NCHW fp32)
    deform_attn_kernel<<<dim3(100, 8, NB), 256, 0, stream>>>(v_s, o4, ref, att);

    // final 1x1 conv -> d_out (NCHW fp32)
    conv1x1_kernel<1><<<dim3(100, NB), 256, 0, stream>>>(att, wto, out_b, (float*)d_out);
}

// Round 5
// 350.928 us; speedup vs baseline: 1.0396x; 1.0396x over previous
//
#include <hip/hip_runtime.h>
#include <math.h>

#define Hh 80
#define Ww 80
#define HW 6400
#define NB 4

typedef _Float16 half8 __attribute__((ext_vector_type(8)));
typedef _Float16 half4v __attribute__((ext_vector_type(4)));
typedef float f32x16 __attribute__((ext_vector_type(16)));

// ---------------------------------------------------------------------------
// Fused weight prep: 4 MFMA A-blobs (fp16) + 2 1x1 transposes (fp32) + zbuf.
// wblob: flat = ((((CT*NC + c)*9 + tap)*2 + h)*64 + lane)*8 + j
//   co = CT*32 + (lane&31);  ci = c*32 + h*16 + (lane>>5)*8 + j
// ---------------------------------------------------------------------------
__device__ inline void wblob_one(const float* src, _Float16* dst, int CI, int d) {
    int NC = CI / 32;
    int j = d & 7;
    int l = (d >> 3) & 63;
    int h = (d >> 9) & 1;
    int rest = d >> 10;
    int tap = rest % 9;
    rest /= 9;
    int c = rest % NC;
    int CT = rest / NC;
    int co = CT * 32 + (l & 31);
    int ci = c * 32 + h * 16 + (l >> 5) * 8 + j;
    dst[d] = (_Float16)src[((size_t)co * CI + ci) * 9 + tap];
}

__global__ void prep_kernel(const float* __restrict__ w1, const float* __restrict__ w2,
                            const float* __restrict__ w3, const float* __restrict__ w4,
                            const float* __restrict__ vw, const float* __restrict__ ow,
                            _Float16* __restrict__ b1, _Float16* __restrict__ b2,
                            _Float16* __restrict__ b3, _Float16* __restrict__ b4,
                            float* __restrict__ tv, float* __restrict__ to,
                            float* __restrict__ zbuf) {
    int idx = blockIdx.x * 256 + threadIdx.x;
    if (idx < 294912) { wblob_one(w1, b1, 256, idx); return; }
    idx -= 294912;
    if (idx < 147456) { wblob_one(w2, b2, 128, idx); return; }
    idx -= 147456;
    if (idx < 147456) { wblob_one(w3, b3, 128, idx); return; }
    idx -= 147456;
    if (idx < 147456) { wblob_one(w4, b4, 128, idx); return; }
    idx -= 147456;
    if (idx < 16384) { int co = idx & 127, ci = idx >> 7; tv[idx] = vw[co * 128 + ci]; return; }
    idx -= 16384;
    if (idx < 16384) { int co = idx & 127, ci = idx >> 7; to[idx] = ow[co * 128 + ci]; return; }
    idx -= 16384;
    if (idx < 256) zbuf[idx] = 0.f;
}

// ---------------------------------------------------------------------------
// fp32 NCHW -> fp16 NHWC transpose. grid (100, N), block 256, 64-site tiles.
// ---------------------------------------------------------------------------
template <int CI>
__global__ __launch_bounds__(256) void nchw_to_nhwc_h(
    const float* __restrict__ in, _Float16* __restrict__ out) {
    const int n = blockIdx.y, s0 = blockIdx.x * 64;
    const int t = threadIdx.x;
    constexpr int ST = CI + 8;
    __shared__ _Float16 T[64 * ST];
    for (int idx = t; idx < 64 * CI; idx += 256) {
        int ci = idx >> 6, sl = idx & 63;
        T[sl * ST + ci] = (_Float16)in[((size_t)n * CI + ci) * HW + s0 + sl];
    }
    __syncthreads();
    constexpr int NQ = CI / 8;
    for (int idx = t; idx < 64 * NQ; idx += 256) {
        int q = idx % NQ, sl = idx / NQ;
        *(int4*)(out + ((size_t)n * HW + s0 + sl) * CI + q * 8) =
            *(const int4*)(&T[sl * ST + q * 8]);
    }
}

// ---------------------------------------------------------------------------
// MFMA implicit-GEMM 3x3 conv, pad=1, fp16 NHWC in. BARRIER-FREE:
// no LDS; B-frags load 16B contiguous from global (L2-resident input);
// OOB taps read a zero buffer (unconditional loads, no branches).
// Single-wave blocks. Wave = 64co (2 co-tiles) x 32sp (8x4 region).
// grid: (200 sp-tiles, 2 co-halves, N).
// ACT 1: leaky -> fp16 NHWC.  ACT 2: 10*tanh -> fp32 NHWC.
// ---------------------------------------------------------------------------
template <int CI, int ACT>
__global__ __launch_bounds__(64) void conv3x3_mfma(
    const _Float16* __restrict__ in, const _Float16* __restrict__ wblob,
    const float* __restrict__ bias, void* __restrict__ outp,
    const _Float16* __restrict__ zbuf) {
    const int bx = blockIdx.x, ch = blockIdx.y, n = blockIdx.z;
    const int x0 = (bx % 10) * 8, y0 = (bx / 10) * 4;
    const int l = threadIdx.x;
    const int lane31 = l & 31, lhalf = l >> 5;
    const int lx = lane31 & 7, ly = lane31 >> 3;
    const int gy = y0 + ly, gx = x0 + lx;
    const int s = gy * 80 + gx;

    constexpr int NC = CI / 32;

    // per-tap site pointers; OOB -> zbuf (>= CI*2 bytes of zeros)
    const _Float16* bptr[9];
#pragma unroll
    for (int tap = 0; tap < 9; ++tap) {
        int dy = tap / 3, dx = tap % 3;
        int yy = gy + dy - 1, xx = gx + dx - 1;
        bool ok = (yy >= 0 && yy < Hh && xx >= 0 && xx < Ww);
        bptr[tap] = ok ? in + ((size_t)n * HW + yy * 80 + xx) * CI : zbuf;
    }

    f32x16 acc0 = {}, acc1 = {};
    const _Float16* w0 = wblob + ((size_t)(ch * 2) * NC * 18) * 512 + l * 8;
    const _Float16* w1 = wblob + ((size_t)(ch * 2 + 1) * NC * 18) * 512 + l * 8;

#pragma unroll 2
    for (int c = 0; c < NC; ++c) {
#pragma unroll
        for (int tap = 0; tap < 9; ++tap) {
#pragma unroll
            for (int h = 0; h < 2; ++h) {
                half8 b  = *(const half8*)(bptr[tap] + c * 32 + h * 16 + lhalf * 8);
                half8 a0 = *(const half8*)(w0 + ((c * 9 + tap) * 2 + h) * 512);
                half8 a1 = *(const half8*)(w1 + ((c * 9 + tap) * 2 + h) * 512);
                acc0 = __builtin_amdgcn_mfma_f32_32x32x16_f16(a0, b, acc0, 0, 0, 0);
                acc1 = __builtin_amdgcn_mfma_f32_32x32x16_f16(a1, b, acc1, 0, 0, 0);
            }
        }
    }

    // epilogue: D col(sp)=lane&31, row(co)=(reg&3)+8*(reg>>2)+4*(lane>>5)
    const size_t rowbase = ((size_t)n * HW + s) * 128;
#pragma unroll
    for (int ct = 0; ct < 2; ++ct) {
        const f32x16& acc = ct ? acc1 : acc0;
        const int co_base = (ch * 2 + ct) * 32;
#pragma unroll
        for (int q = 0; q < 4; ++q) {
            const int co0 = co_base + 8 * q + 4 * lhalf;
            float v[4];
#pragma unroll
            for (int i = 0; i < 4; ++i) {
                float vv = acc[q * 4 + i] + bias[co0 + i];
                if (ACT == 1) vv = (vv >= 0.f) ? vv : 0.1f * vv;
                else vv = 10.f * tanhf(vv);
                v[i] = vv;
            }
            if (ACT == 1) {
                half4v hv = {(_Float16)v[0], (_Float16)v[1], (_Float16)v[2], (_Float16)v[3]};
                *(half4v*)((_Float16*)outp + rowbase + co0) = hv;
            } else {
                float4 fv = {v[0], v[1], v[2], v[3]};
                *(float4*)((float*)outp + rowbase + co0) = fv;
            }
        }
    }
}

// ---------------------------------------------------------------------------
// 1x1 conv (fp32 GEMM 128x128 over spatial). grid: (100, N), block 256.
// wt layout: [ci][128co].
// MODE 0: in fp32 NCHW  -> out v_s NHWC-16.
// MODE 1: in fp32 NHWC-16 ([n*8+hd][s][16]) -> out NCHW.
// ---------------------------------------------------------------------------
template <int MODE>
__global__ __launch_bounds__(256) void conv1x1_kernel(
    const float* __restrict__ in, const float* __restrict__ wt,
    const float* __restrict__ bias, float* __restrict__ out) {
    const int n = blockIdx.y;
    const int s0 = blockIdx.x * 64;
    const int t = threadIdx.x;
    const int sp_grp = t & 15;
    const int co_grp = t >> 4;

    __shared__ float Wl[16 * 128];
    __shared__ float Il[16 * 64];

    float acc[8][4];
#pragma unroll
    for (int i = 0; i < 8; ++i)
#pragma unroll
        for (int j = 0; j < 4; ++j) acc[i][j] = 0.f;

    for (int ch = 0; ch < 8; ++ch) {
        const int ci0 = ch * 16;
        __syncthreads();
        for (int i = t; i < 16 * 128; i += 256) Wl[i] = wt[ci0 * 128 + i];
        if (MODE == 0) {
            for (int i = t; i < 16 * 64; i += 256) {
                int ci = i >> 6, sp = i & 63;
                Il[i] = in[(size_t)(n * 128 + ci0 + ci) * HW + s0 + sp];
            }
        } else {
            // NHWC-16 input: ci-chunk == head ch; 4 lanes fetch one site's 16 floats
            int grp = t & 3, sp = t >> 2;
            const float4 v = *(const float4*)&in[(((size_t)(n * 8 + ch)) * HW + s0 + sp) * 16 + grp * 4];
            Il[(grp * 4 + 0) * 64 + sp] = v.x;
            Il[(grp * 4 + 1) * 64 + sp] = v.y;
            Il[(grp * 4 + 2) * 64 + sp] = v.z;
            Il[(grp * 4 + 3) * 64 + sp] = v.w;
        }
        __syncthreads();
#pragma unroll
        for (int ci = 0; ci < 16; ++ci) {
            float4 a0 = *(const float4*)&Wl[ci * 128 + co_grp * 8];
            float4 a1 = *(const float4*)&Wl[ci * 128 + co_grp * 8 + 4];
            float4 b  = *(const float4*)&Il[ci * 64 + sp_grp * 4];
            float av[8] = {a0.x, a0.y, a0.z, a0.w, a1.x, a1.y, a1.z, a1.w};
            float bv[4] = {b.x, b.y, b.z, b.w};
#pragma unroll
            for (int i = 0; i < 8; ++i)
#pragma unroll
                for (int j = 0; j < 4; ++j)
                    acc[i][j] = fmaf(av[i], bv[j], acc[i][j]);
        }
    }

#pragma unroll
    for (int i = 0; i < 8; ++i) {
        const int co = co_grp * 8 + i;
        const float bv = bias[co];
        if (MODE == 0) {
            const int hd = co >> 4, dd = co & 15;
#pragma unroll
            for (int j = 0; j < 4; ++j) {
                int s = s0 + sp_grp * 4 + j;
                out[((size_t)(n * 8 + hd) * HW + s) * 16 + dd] = acc[i][j] + bv;
            }
        } else {
#pragma unroll
            for (int j = 0; j < 4; ++j)
                out[(size_t)(n * 128 + co) * HW + s0 + sp_grp * 4 + j] = acc[i][j] + bv;
        }
    }
}

// ---------------------------------------------------------------------------
// Deformable attention, channel-vectorized + XCD-pinned slices.
// grid: (32 slices, 100 tiles), block 256 = 64 sites x 4 chgrp.
// Linear block id = slice + 32*tile -> XCD = slice%8 = head: all blocks of
// head h land on XCD h; its 4 slices (4 n) = 1.6 MB stay in that L2.
// v_s [nb][s][16] fp32; offs NHWC fp32; att NHWC-16 fp32.
// ---------------------------------------------------------------------------
__global__ __launch_bounds__(256) void deform_attn_kernel(
    const float* __restrict__ v_s, const float* __restrict__ offs,
    const float* __restrict__ ref, float* __restrict__ att) {
    const int slice = blockIdx.x;
    const int n = slice >> 3, hd = slice & 7;
    const int t = threadIdx.x;
    const int s = blockIdx.y * 64 + (t >> 2);
    const int d0 = (t & 3) * 4;
    const int nb = n * 8 + hd;

    const float4 cv = *(const float4*)&v_s[((size_t)nb * HW + s) * 16 + d0];
    const float rx = ref[(size_t)(n * HW + s) * 2 + 0] * 80.f - 0.5f;
    const float ry = ref[(size_t)(n * HW + s) * 2 + 1] * 80.f - 0.5f;

    const int e = (s >= 3200) ? 1 : 0;
    const float* ob0 = offs + ((size_t)n * HW + (2 * s - e * HW)) * 128 + hd * 16 + e;

    float4 sampled[8];
    float score[8];
#pragma unroll
    for (int p = 0; p < 8; ++p) {
        const float ox = ob0[2 * p];
        const float oy = ob0[128 + 2 * p];
        const float px = rx + ox;
        const float py = ry + oy;
        const float fx = floorf(px), fy = floorf(py);
        const int ix = (int)fx, iy = (int)fy;
        const float wx1 = px - fx, wy1 = py - fy;
        const float wx0 = 1.f - wx1, wy0 = 1.f - wy1;

        auto samp = [&](int xx, int yy) -> float4 {
            if (xx < 0 || xx >= Ww || yy < 0 || yy >= Hh) {
                float4 z = {0.f, 0.f, 0.f, 0.f};
                return z;
            }
            return *(const float4*)&v_s[((size_t)nb * HW + yy * Ww + xx) * 16 + d0];
        };
        const float4 v00 = samp(ix, iy);
        const float4 v01 = samp(ix + 1, iy);
        const float4 v10 = samp(ix, iy + 1);
        const float4 v11 = samp(ix + 1, iy + 1);
        const float w00 = wx0 * wy0, w01 = wx1 * wy0, w10 = wx0 * wy1, w11 = wx1 * wy1;
        float4 sv;
        sv.x = v00.x * w00 + v01.x * w01 + v10.x * w10 + v11.x * w11;
        sv.y = v00.y * w00 + v01.y * w01 + v10.y * w10 + v11.y * w11;
        sv.z = v00.z * w00 + v01.z * w01 + v10.z * w10 + v11.z * w11;
        sv.w = v00.w * w00 + v01.w * w01 + v10.w * w10 + v11.w * w11;
        sampled[p] = sv;
        float sc = sv.x * cv.x + sv.y * cv.y + sv.z * cv.z + sv.w * cv.w;
        sc += __shfl_xor(sc, 1);
        sc += __shfl_xor(sc, 2);
        score[p] = sc;
    }

    float m = score[0];
#pragma unroll
    for (int p = 1; p < 8; ++p) m = fmaxf(m, score[p]);
    float sum = 0.f, aw[8];
#pragma unroll
    for (int p = 0; p < 8; ++p) {
        aw[p] = __expf(score[p] - m);
        sum += aw[p];
    }
    const float inv = 1.f / sum;
    float4 o = {0.f, 0.f, 0.f, 0.f};
#pragma unroll
    for (int p = 0; p < 8; ++p) {
        o.x += aw[p] * sampled[p].x;
        o.y += aw[p] * sampled[p].y;
        o.z += aw[p] * sampled[p].z;
        o.w += aw[p] * sampled[p].w;
    }
    o.x *= inv; o.y *= inv; o.z *= inv; o.w *= inv;

    *(float4*)&att[((size_t)nb * HW + s) * 16 + d0] = o;
}

// ---------------------------------------------------------------------------
extern "C" void kernel_launch(void* const* d_in, const int* in_sizes, int n_in,
                              void* d_out, int out_size, void* d_ws, size_t ws_size,
                              hipStream_t stream) {
    const float* query = (const float*)d_in[0];
    const float* value = (const float*)d_in[1];
    const float* ref   = (const float*)d_in[2];
    const float* co_w1 = (const float*)d_in[3];
    const float* co_b1 = (const float*)d_in[4];
    const float* co_w2 = (const float*)d_in[5];
    const float* co_b2 = (const float*)d_in[6];
    const float* co_w3 = (const float*)d_in[7];
    const float* co_b3 = (const float*)d_in[8];
    const float* co_w4 = (const float*)d_in[9];
    const float* co_b4 = (const float*)d_in[10];
    const float* val_w = (const float*)d_in[11];
    const float* val_b = (const float*)d_in[12];
    const float* out_w = (const float*)d_in[13];
    const float* out_b = (const float*)d_in[14];

    char* ws = (char*)d_ws;
    size_t o = 0;
    auto alloc = [&](size_t bytes) { char* p = ws + o; o += (bytes + 255) & ~(size_t)255; return p; };

    _Float16* wb2 = (_Float16*)alloc(147456 * 2);
    _Float16* wb3 = (_Float16*)alloc(147456 * 2);
    _Float16* wb4 = (_Float16*)alloc(147456 * 2);
    float* wtv = (float*)alloc(16384 * 4);
    float* wto = (float*)alloc(16384 * 4);
    float* zbuf = (float*)alloc(256 * 4);      // 1 KB zeros for OOB conv taps
    char* vsR = alloc(3276800 * 4);            // v_s fp32 [32][6400][16]
    float* v_s = (float*)vsR;
    _Float16* wb1 = (_Float16*)vsR;            // alias: wb1 dead before v_s written
    char* R1 = alloc(3276800 * 4);
    _Float16* q_h = (_Float16*)R1;             // fp16 NHWC [4][6400][256] (13.1 MB)
    float* o4 = (float*)R1;                    // fp32 NHWC [4][6400][128]; q_h dead
    char* R2 = alloc(3276800 * 4);
    _Float16* hA = (_Float16*)R2;              // fp16 NHWC [4][6400][128]
    _Float16* hB = (_Float16*)(R2 + 3276800 * 2);
    float* att = (float*)R2;                   // NHWC-16 fp32; used after hA/hB dead

    // fused prep: wblobs + 1x1 transposes + zbuf
    prep_kernel<<<3010, 256, 0, stream>>>(co_w1, co_w2, co_w3, co_w4, val_w, out_w,
                                          wb1, wb2, wb3, wb4, wtv, wto, zbuf);

    // transpose query to fp16 NHWC
    nchw_to_nhwc_h<256><<<dim3(100, NB), 256, 0, stream>>>(query, q_h);

    // conv1 (must precede val-conv: wb1 aliases v_s region)
    conv3x3_mfma<256, 1><<<dim3(200, 2, NB), 64, 0, stream>>>(q_h, wb1, co_b1, hA, (const _Float16*)zbuf);

    // v = 1x1 conv(value) -> v_s (NHWC-16 fp32)
    conv1x1_kernel<0><<<dim3(100, NB), 256, 0, stream>>>(value, wtv, val_b, v_s);

    // rest of offset conv stack
    conv3x3_mfma<128, 1><<<dim3(200, 2, NB), 64, 0, stream>>>(hA, wb2, co_b2, hB, (const _Float16*)zbuf);
    conv3x3_mfma<128, 1><<<dim3(200, 2, NB), 64, 0, stream>>>(hB, wb3, co_b3, hA, (const _Float16*)zbuf);
    conv3x3_mfma<128, 2><<<dim3(200, 2, NB), 64, 0, stream>>>(hA, wb4, co_b4, o4, (const _Float16*)zbuf);

    // deformable attention -> att (NHWC-16 fp32), XCD-pinned slices
    deform_attn_kernel<<<dim3(32, 100), 256, 0, stream>>>(v_s, o4, ref, att);

    // final 1x1 conv -> d_out (NCHW fp32)
    conv1x1_kernel<1><<<dim3(100, NB), 256, 0, stream>>>(att, wto, out_b, (float*)d_out);
}